// Round 6
// baseline (843.674 us; speedup 1.0000x reference)
//
#include <hip/hip_runtime.h>
#include <stdint.h>

typedef unsigned short u16;

#define TN    84768      // B*T*N = 8*12*883
#define NNODE 883
#define DD    128
#define EE    7000
#define FFDIM 2048

typedef short bf16x8 __attribute__((ext_vector_type(8)));
typedef float f32x4  __attribute__((ext_vector_type(4)));

__device__ __forceinline__ float bf2f(u16 u) {
    unsigned int x = ((unsigned int)u) << 16;
    return __uint_as_float(x);
}
__device__ __forceinline__ u16 f2bf(float f) {
    unsigned int x = __float_as_uint(f);
    x += 0x7FFFu + ((x >> 16) & 1u);   // round-to-nearest-even
    return (u16)(x >> 16);
}
// sanitize: any Inf/NaN bit pattern -> 0
__device__ __forceinline__ u16 cleanu(u16 u) {
    return (((u >> 7) & 0xFF) == 0xFF) ? (u16)0 : u;
}
__device__ __forceinline__ u16 cleanf(float f) {
    unsigned b = __float_as_uint(f);
    if (((b >> 23) & 0xFF) == 0xFF) return 0;
    return cleanu(f2bf(f));
}
__device__ __forceinline__ float loadx(const void* p, size_t i, int f32) {
    if (f32) {
        float v = ((const float*)p)[i];
        unsigned b = __float_as_uint(v);
        if (((b >> 23) & 0xFF) == 0xFF) v = 0.f;
        return v;
    }
    return bf2f(cleanu(((const u16*)p)[i]));
}

// -------- dtype detect: bf16-packed vs fp32 --------
__global__ __launch_bounds__(256) void k_detect(const unsigned* __restrict__ x,
                                                int* __restrict__ flag) {
    __shared__ int cnt;
    if (threadIdx.x == 0) cnt = 0;
    __syncthreads();
    unsigned w = x[threadIdx.x];
    unsigned e = (w >> 7) & 0xFF;
    int ok = (e >= 96 && e <= 144) || ((w & 0xFFFFu) == 0);
    atomicAdd(&cnt, ok);
    __syncthreads();
    if (threadIdx.x == 0) flag[0] = (cnt < 200) ? 1 : 0;   // 1 = fp32
}

// -------- convert+sanitize param vectors into one canon buffer --------
// canon u16 offsets: bl 0, br 128, att 256, bgat 384, b1 512, b2 2560,
//                    g1 2688, be1 2816, g2 2944, be2 3072
__global__ __launch_bounds__(256) void k_params(const void* bl, const void* br,
                                                const void* att, const void* bgat,
                                                const void* b1, const void* b2,
                                                const void* g1, const void* be1,
                                                const void* g2, const void* be2,
                                                u16* __restrict__ canon,
                                                const int* __restrict__ flag) {
    int f32 = *flag;
    int i = blockIdx.x * 256 + threadIdx.x;
    const void* src; int off;
    if      (i < 128)  { src = bl;   off = 0; }
    else if (i < 256)  { src = br;   off = 128; }
    else if (i < 384)  { src = att;  off = 256; }
    else if (i < 512)  { src = bgat; off = 384; }
    else if (i < 2560) { src = b1;   off = 512; }
    else if (i < 2688) { src = b2;   off = 2560; }
    else if (i < 2816) { src = g1;   off = 2688; }
    else if (i < 2944) { src = be1;  off = 2816; }
    else if (i < 3072) { src = g2;   off = 2944; }
    else if (i < 3200) { src = be2;  off = 3072; }
    else return;
    int j = i - off;
    canon[i] = f32 ? cleanf(((const float*)src)[j]) : cleanu(((const u16*)src)[j]);
}

// -------- convert+sanitize+transpose weights [R][C] -> bf16 [C][R] --------
__global__ __launch_bounds__(256) void k_t2(const void* __restrict__ in,
                                            u16* __restrict__ out, int R, int Cc,
                                            const int* __restrict__ flag) {
    int f32 = *flag;
    int i = blockIdx.x * 256 + threadIdx.x;
    if (i < R * Cc) {
        int r = i / Cc, c = i - r * Cc;
        u16 v = f32 ? cleanf(((const float*)in)[i]) : cleanu(((const u16*)in)[i]);
        out[c * R + r] = v;
    }
}

// -------- CSR of the shared 7000-edge graph (dst-indexed); int32/int64 auto --------
__global__ __launch_bounds__(1024) void k_csr(const int* __restrict__ ew,
                                              int* __restrict__ row_off,
                                              int* __restrict__ col) {
    __shared__ int cnt[NNODE];
    __shared__ int offs[NNODE + 1];
    __shared__ int cur[NNODE];
    __shared__ int flag;
    int tid = threadIdx.x;
    if (tid == 0) flag = 0;
    for (int i = tid; i < NNODE; i += 1024) cnt[i] = 0;
    __syncthreads();
    int f = 0;
    for (int j = tid; j < EE; j += 1024) f |= ew[2 * j + 1];
    if (f) atomicOr(&flag, 1);
    __syncthreads();
    bool is32 = (flag != 0);
    for (int e = tid; e < EE; e += 1024) {
        int dst = is32 ? ew[EE + e] : ew[2 * EE + 2 * e];
        if ((unsigned)dst < NNODE) atomicAdd(&cnt[dst], 1);
    }
    __syncthreads();
    if (tid == 0) {
        int run = 0;
        for (int i = 0; i < NNODE; ++i) { offs[i] = run; run += cnt[i]; }
        offs[NNODE] = run;
    }
    __syncthreads();
    for (int i = tid; i < NNODE; i += 1024) cur[i] = offs[i];
    __syncthreads();
    for (int e = tid; e < EE; e += 1024) {
        int src = is32 ? ew[e] : ew[2 * e];
        int dst = is32 ? ew[EE + e] : ew[2 * EE + 2 * e];
        if ((unsigned)dst < NNODE && (unsigned)src < NNODE) {
            int p = atomicAdd(&cur[dst], 1);
            if (p < EE) col[p] = src;
        }
    }
    __syncthreads();
    for (int i = tid; i <= NNODE; i += 1024) row_off[i] = offs[i];
}

// -------- x_l / x_r: [TN,128] @ [128,256] via MFMA --------
__global__ __launch_bounds__(256) void k_linlr(const void* __restrict__ xraw,
                                               const u16* __restrict__ wlrT,  // [256][128]
                                               const u16* __restrict__ canon,
                                               u16* __restrict__ xl, u16* __restrict__ xr,
                                               const int* __restrict__ flag) {
    __shared__ __align__(16) u16 a_tile[64 * 136];
    int f32 = *flag;
    int tid = threadIdx.x;
    int m0 = blockIdx.x * 64;
    for (int it = 0; it < 4; ++it) {
        int idx = it * 256 + tid;
        int row = idx >> 4, cc = idx & 15;
        int gm = m0 + row;
        u16 tmp[8];
#pragma unroll
        for (int j = 0; j < 8; ++j) tmp[j] = 0;
        if (gm < TN) {
            size_t base = (size_t)gm * DD + cc * 8;
            if (f32) {
                float4 v0 = *(const float4*)((const float*)xraw + base);
                float4 v1 = *(const float4*)((const float*)xraw + base + 4);
                tmp[0] = cleanf(v0.x); tmp[1] = cleanf(v0.y);
                tmp[2] = cleanf(v0.z); tmp[3] = cleanf(v0.w);
                tmp[4] = cleanf(v1.x); tmp[5] = cleanf(v1.y);
                tmp[6] = cleanf(v1.z); tmp[7] = cleanf(v1.w);
            } else {
                uint4 v = *(const uint4*)((const u16*)xraw + base);
                unsigned wv[4] = {v.x, v.y, v.z, v.w};
#pragma unroll
                for (int j = 0; j < 8; ++j)
                    tmp[j] = cleanu((u16)((wv[j >> 1] >> ((j & 1) * 16)) & 0xFFFFu));
            }
        }
        uint4 o;
        o.x = (unsigned)tmp[0] | ((unsigned)tmp[1] << 16);
        o.y = (unsigned)tmp[2] | ((unsigned)tmp[3] << 16);
        o.z = (unsigned)tmp[4] | ((unsigned)tmp[5] << 16);
        o.w = (unsigned)tmp[6] | ((unsigned)tmp[7] << 16);
        *(uint4*)(a_tile + row * 136 + cc * 8) = o;
    }
    __syncthreads();
    int wave = tid >> 6, lane = tid & 63, n16 = lane & 15, q = lane >> 4;
    f32x4 acc[16];
#pragma unroll
    for (int t = 0; t < 16; ++t) acc[t] = (f32x4){0, 0, 0, 0};
    const u16* arow = a_tile + (16 * wave + n16) * 136;
#pragma unroll
    for (int ks = 0; ks < 4; ++ks) {
        bf16x8 a = *(const bf16x8*)(arow + ks * 32 + q * 8);
#pragma unroll
        for (int t = 0; t < 16; ++t) {
            bf16x8 b = *(const bf16x8*)(wlrT + ((size_t)(t * 16 + n16)) * DD + ks * 32 + q * 8);
            acc[t] = __builtin_amdgcn_mfma_f32_16x16x32_bf16(a, b, acc[t], 0, 0, 0);
        }
    }
#pragma unroll
    for (int t = 0; t < 16; ++t) {
        int cc = (t & 7) * 16 + n16;
        float bias = bf2f(canon[(t < 8 ? 0 : 128) + cc]);
        u16* dst = (t < 8 ? xl : xr);
#pragma unroll
        for (int reg = 0; reg < 4; ++reg) {
            int mrow = m0 + 16 * wave + 4 * q + reg;
            if (mrow < TN) dst[(size_t)mrow * DD + cc] = f2bf(acc[t][reg] + bias);
        }
    }
}

// -------- 16-lane segment sum --------
__device__ __forceinline__ float segsum16(float p) {
    p += __shfl_xor(p, 1, 16);
    p += __shfl_xor(p, 2, 16);
    p += __shfl_xor(p, 4, 16);
    p += __shfl_xor(p, 8, 16);
    return p;
}

// -------- GATv2: single-pass online softmax + residual + LN1 --------
__global__ __launch_bounds__(256) void k_gat(const void* __restrict__ xraw,
                                             const u16* __restrict__ xl,
                                             const u16* xr,
                                             const u16* __restrict__ canon,
                                             const int* __restrict__ row_off,
                                             const int* __restrict__ col,
                                             u16* h1,
                                             const int* __restrict__ flag) {
    int f32 = *flag;
    int tid = threadIdx.x;
    int local = tid >> 7;
    int d = tid & 127;
    int g = blockIdx.x * 2 + local;            // TN even
    int bt = g / NNODE;
    int i = g - bt * NNODE;
    size_t gbase = (size_t)g * DD;
    size_t nbase = (size_t)bt * NNODE;
    float xr_d = bf2f(xr[gbase + d]);
    float att_d = bf2f(canon[256 + d]);
    float xl_self = bf2f(xl[gbase + d]);
    int r0 = row_off[i], r1 = row_off[i + 1];
    // online softmax: start with the self-loop
    float t0 = xl_self + xr_d; t0 = t0 > 0.f ? t0 : 0.2f * t0;
    float m = segsum16(t0 * att_d);
    float denom = 1.f;
    float acc = xl_self;
    for (int e = r0; e < r1; ++e) {
        int j = col[e];
        if ((unsigned)j >= NNODE) continue;
        float xlj = bf2f(xl[(nbase + j) * DD + d]);
        float t = xlj + xr_d; t = t > 0.f ? t : 0.2f * t;
        float s = segsum16(t * att_d);
        float mn = fmaxf(m, s);
        float eo = __expf(m - mn);
        float en = __expf(s - mn);
        denom = denom * eo + en;
        acc = acc * eo + en * xlj;
        m = mn;
    }
    float pre = acc / denom + bf2f(canon[384 + d]) + loadx(xraw, gbase + d, f32);
    // LN1 across 128 channels (2 waves per node)
    float sum = pre, sq = pre * pre;
    for (int off = 32; off; off >>= 1) {
        sum += __shfl_xor(sum, off);
        sq  += __shfl_xor(sq, off);
    }
    __shared__ float part[2][2][2];
    int win = (tid >> 6) & 1;
    if ((tid & 63) == 0) { part[local][win][0] = sum; part[local][win][1] = sq; }
    __syncthreads();
    float ts = part[local][0][0] + part[local][1][0];
    float tq = part[local][0][1] + part[local][1][1];
    float mu = ts * (1.0f / 128.0f);
    float var = fmaxf(tq * (1.0f / 128.0f) - mu * mu, 0.f);
    float rs = rsqrtf(var + 1e-5f);
    float hv = (pre - mu) * rs * bf2f(canon[2688 + d]) + bf2f(canon[2816 + d]);
    h1[gbase + d] = f2bf(hv);
}

// -------- fused FFN + residual + LN2: M=64/block, wave=16 rows --------
// Register-prefetched weight pipeline; s-tile aliased into w1b (wave-private
// rows, separated from w1b b-frag reads by a barrier). LDS = 34816 B.
__global__ __launch_bounds__(256, 4) void k_ffn(const u16* __restrict__ h1,
                                                const u16* __restrict__ w1T,  // [2048][128]
                                                const u16* __restrict__ w2T,  // [128][2048]
                                                const u16* __restrict__ canon,
                                                void* __restrict__ outraw,
                                                const int* __restrict__ flag) {
    __shared__ __align__(16) u16 w1b[64 * 136];   // W1 chunk; also hosts s (wave rows)
    __shared__ __align__(16) u16 w2b[128 * 68];   // W2 chunk
    int f32 = *flag;
    int tid = threadIdx.x;
    int wave = tid >> 6, lane = tid & 63, n16 = lane & 15, q = lane >> 4;
    int m0 = blockIdx.x * 64;
    // A-fragments of h for this wave's 16 rows, in registers all kernel
    bf16x8 af[4];
    {
        int gm = m0 + 16 * wave + n16;
#pragma unroll
        for (int ks = 0; ks < 4; ++ks) {
            if (gm < TN) {
                uint4 v = *(const uint4*)(h1 + (size_t)gm * DD + ks * 32 + q * 8);
                af[ks] = *(const bf16x8*)&v;
            } else {
                uint4 z = make_uint4(0, 0, 0, 0);
                af[ks] = *(const bf16x8*)&z;
            }
        }
    }
    f32x4 acc2[8];
#pragma unroll
    for (int t = 0; t < 8; ++t) acc2[t] = (f32x4){0, 0, 0, 0};
    // staging split: W1 64 rows x 4 segs of 32 u16; W2 128 rows x 2 segs
    int r1s = tid >> 2, seg1 = tid & 3;
    int r2s = tid >> 1, seg2 = tid & 1;
    const uint4* g1p = (const uint4*)(w1T + (size_t)r1s * DD + seg1 * 32);
    const uint4* g2p = (const uint4*)(w2T + (size_t)r2s * FFDIM + seg2 * 32);
    uint4* l1p = (uint4*)(w1b + r1s * 136 + seg1 * 32);
    uint4* l2p = (uint4*)(w2b + r2s * 68 + seg2 * 32);
    u16* srow_w = w1b + (16 * wave + 4 * q) * 136;          // s write base (own rows)
    const u16* srow_r = w1b + (16 * wave + n16) * 136;      // s read base (own rows)
    // prologue: prefetch chunk 0
    uint4 pf1[4], pf2[4];
#pragma unroll
    for (int i = 0; i < 4; ++i) pf1[i] = g1p[i * 2];        // rows stride: 4 uint4 = 64B = row seg
#pragma unroll
    for (int i = 0; i < 4; ++i) pf2[i] = g2p[i];
    // NOTE: W1 thread slice is 4 consecutive uint4 (64 B) in one row; fix index:
    // g1p already points at the thread's 64 B slice; elements 0..3 are right.
#pragma unroll
    for (int i = 0; i < 4; ++i) pf1[i] = g1p[i];
    for (int ch = 0; ch < 32; ++ch) {
        __syncthreads();   // prev chunk's w1b/w2b/s consumers done
#pragma unroll
        for (int i = 0; i < 4; ++i) l1p[i] = pf1[i];
#pragma unroll
        for (int i = 0; i < 4; ++i) l2p[i] = pf2[i];
        if (ch < 31) {     // prefetch next chunk (in flight across compute)
            const uint4* n1 = (const uint4*)((const u16*)g1p + (ch + 1) * 64 * DD);
            const uint4* n2 = (const uint4*)((const u16*)g2p + (ch + 1) * 64);
#pragma unroll
            for (int i = 0; i < 4; ++i) pf1[i] = n1[i];
#pragma unroll
            for (int i = 0; i < 4; ++i) pf2[i] = n2[i];
        }
        __syncthreads();   // staging visible
        int f0 = ch * 64;
        // GEMM1: s_cols = relu(h @ W1chunk + b1), t-sequential (low VGPR)
        float sval[4][4];  // [t][reg]
#pragma unroll
        for (int t = 0; t < 4; ++t) {
            f32x4 a1 = (f32x4){0, 0, 0, 0};
#pragma unroll
            for (int ks = 0; ks < 4; ++ks) {
                bf16x8 b = *(const bf16x8*)(w1b + (t * 16 + n16) * 136 + ks * 32 + q * 8);
                a1 = __builtin_amdgcn_mfma_f32_16x16x32_bf16(af[ks], b, a1, 0, 0, 0);
            }
            float bb = bf2f(canon[512 + f0 + t * 16 + n16]);
#pragma unroll
            for (int reg = 0; reg < 4; ++reg) {
                float v = a1[reg] + bb;
                sval[t][reg] = v > 0.f ? v : 0.f;
            }
        }
        __syncthreads();   // all waves done reading w1b before s overwrites it
#pragma unroll
        for (int t = 0; t < 4; ++t)
#pragma unroll
            for (int reg = 0; reg < 4; ++reg)
                srow_w[reg * 136 + t * 16 + n16] = f2bf(sval[t][reg]);
        asm volatile("" ::: "memory");
        // GEMM2: acc2 += s @ W2chunk (s rows are wave-private; per-wave order ok)
#pragma unroll
        for (int ks2 = 0; ks2 < 2; ++ks2) {
            bf16x8 a2 = *(const bf16x8*)(srow_r + ks2 * 32 + q * 8);
#pragma unroll
            for (int t = 0; t < 8; ++t) {
                bf16x8 b = *(const bf16x8*)(w2b + (t * 16 + n16) * 68 + ks2 * 32 + q * 8);
                acc2[t] = __builtin_amdgcn_mfma_f32_16x16x32_bf16(a2, b, acc2[t], 0, 0, 0);
            }
        }
        asm volatile("" ::: "memory");
    }
    // epilogue: +b2 +residual, LN2 via 16-lane shuffles (row lives in one quad)
    float b2v[8], g2v[8], e2v[8];
#pragma unroll
    for (int t = 0; t < 8; ++t) {
        int col = t * 16 + n16;
        b2v[t] = bf2f(canon[2560 + col]);
        g2v[t] = bf2f(canon[2944 + col]);
        e2v[t] = bf2f(canon[3072 + col]);
    }
#pragma unroll
    for (int reg = 0; reg < 4; ++reg) {
        int row = 16 * wave + 4 * q + reg;
        int gm = m0 + row;
        bool ok = gm < TN;
        size_t gb = (size_t)(ok ? gm : 0) * DD;
        float v[8]; float s1 = 0.f, s2 = 0.f;
#pragma unroll
        for (int t = 0; t < 8; ++t) {
            float hres = bf2f(h1[gb + t * 16 + n16]);
            v[t] = acc2[t][reg] + b2v[t] + hres;
            s1 += v[t]; s2 += v[t] * v[t];
        }
        s1 = segsum16(s1);
        s2 = segsum16(s2);
        float mu = s1 * (1.f / 128.f);
        float var = fmaxf(s2 * (1.f / 128.f) - mu * mu, 0.f);
        float rs = rsqrtf(var + 1e-5f);
        if (ok) {
#pragma unroll
            for (int t = 0; t < 8; ++t) {
                float r = (v[t] - mu) * rs * g2v[t] + e2v[t];
                if (f32) ((float*)outraw)[gb + t * 16 + n16] = r;
                else     ((u16*)outraw)[gb + t * 16 + n16] = f2bf(r);
            }
        }
    }
}

extern "C" void kernel_launch(void* const* d_in, const int* in_sizes, int n_in,
                              void* d_out, int out_size, void* d_ws, size_t ws_size,
                              hipStream_t stream) {
    const void* x    = d_in[0];
    const int* eidx  = (const int*)d_in[1];
    const void* Wl   = d_in[2];
    const void* bl   = d_in[3];
    const void* Wr   = d_in[4];
    const void* br   = d_in[5];
    const void* att  = d_in[6];
    const void* bgat = d_in[7];
    const void* W1   = d_in[8];
    const void* b1   = d_in[9];
    const void* W2   = d_in[10];
    const void* b2   = d_in[11];
    const void* g1   = d_in[12];
    const void* be1  = d_in[13];
    const void* g2   = d_in[14];
    const void* be2  = d_in[15];

    // ws layout (bytes): flag@0, rowoff@4096, colw@8192, canon@36864,
    // wlrT@65536, w1T@131072, w2T@655360, xl@1179648, xr/h1@22880256
    char* ws = (char*)d_ws;
    int* flag   = (int*)(ws);
    int* rowoff = (int*)(ws + 4096);
    int* colw   = (int*)(ws + 8192);
    u16* canon  = (u16*)(ws + 36864);
    u16* wlrT   = (u16*)(ws + 65536);
    u16* w1T    = (u16*)(ws + 131072);
    u16* w2T    = (u16*)(ws + 655360);
    u16* xl     = (u16*)(ws + 1179648);
    u16* xr     = (u16*)(ws + 22880256);
    u16* h1     = xr;   // k_gat reads xr[addr] before writing h1[addr]

    k_detect<<<1, 256, 0, stream>>>((const unsigned*)x, flag);
    k_params<<<13, 256, 0, stream>>>(bl, br, att, bgat, b1, b2, g1, be1, g2, be2,
                                     canon, flag);
    k_t2<<<64, 256, 0, stream>>>(Wl, wlrT, 128, 128, flag);
    k_t2<<<64, 256, 0, stream>>>(Wr, wlrT + 16384, 128, 128, flag);
    k_t2<<<1024, 256, 0, stream>>>(W1, w1T, 128, 2048, flag);
    k_t2<<<1024, 256, 0, stream>>>(W2, w2T, 2048, 128, flag);
    k_csr<<<1, 1024, 0, stream>>>(eidx, rowoff, colw);
    k_linlr<<<(TN + 63) / 64, 256, 0, stream>>>(x, wlrT, canon, xl, xr, flag);
    k_gat<<<TN / 2, 256, 0, stream>>>(x, xl, xr, canon, rowoff, colw, h1, flag);
    k_ffn<<<(TN + 63) / 64, 256, 0, stream>>>(h1, w1T, w2T, canon, d_out, flag);
}

// Round 7
// 537.737 us; speedup vs baseline: 1.5689x; 1.5689x over previous
//
#include <hip/hip_runtime.h>
#include <stdint.h>

typedef unsigned short u16;

#define TN    84768      // B*T*N = 8*12*883
#define NNODE 883
#define DD    128
#define EE    7000
#define FFDIM 2048

typedef short bf16x8 __attribute__((ext_vector_type(8)));
typedef float f32x4  __attribute__((ext_vector_type(4)));
typedef __attribute__((address_space(3))) u16 lds_u16;
typedef const __attribute__((address_space(1))) u16 glb_u16;

__device__ __forceinline__ float bf2f(u16 u) {
    unsigned int x = ((unsigned int)u) << 16;
    return __uint_as_float(x);
}
__device__ __forceinline__ u16 f2bf(float f) {
    unsigned int x = __float_as_uint(f);
    x += 0x7FFFu + ((x >> 16) & 1u);   // round-to-nearest-even
    return (u16)(x >> 16);
}
// sanitize: any Inf/NaN bit pattern -> 0
__device__ __forceinline__ u16 cleanu(u16 u) {
    return (((u >> 7) & 0xFF) == 0xFF) ? (u16)0 : u;
}
__device__ __forceinline__ u16 cleanf(float f) {
    unsigned b = __float_as_uint(f);
    if (((b >> 23) & 0xFF) == 0xFF) return 0;
    return cleanu(f2bf(f));
}
__device__ __forceinline__ float loadx(const void* p, size_t i, int f32) {
    if (f32) {
        float v = ((const float*)p)[i];
        unsigned b = __float_as_uint(v);
        if (((b >> 23) & 0xFF) == 0xFF) v = 0.f;
        return v;
    }
    return bf2f(cleanu(((const u16*)p)[i]));
}

// -------- dtype detect: bf16-packed vs fp32 --------
__global__ __launch_bounds__(256) void k_detect(const unsigned* __restrict__ x,
                                                int* __restrict__ flag) {
    __shared__ int cnt;
    if (threadIdx.x == 0) cnt = 0;
    __syncthreads();
    unsigned w = x[threadIdx.x];
    unsigned e = (w >> 7) & 0xFF;
    int ok = (e >= 96 && e <= 144) || ((w & 0xFFFFu) == 0);
    atomicAdd(&cnt, ok);
    __syncthreads();
    if (threadIdx.x == 0) flag[0] = (cnt < 200) ? 1 : 0;   // 1 = fp32
}

// -------- convert+sanitize param vectors into one canon buffer --------
// canon u16 offsets: bl 0, br 128, att 256, bgat 384, b1 512, b2 2560,
//                    g1 2688, be1 2816, g2 2944, be2 3072
__global__ __launch_bounds__(256) void k_params(const void* bl, const void* br,
                                                const void* att, const void* bgat,
                                                const void* b1, const void* b2,
                                                const void* g1, const void* be1,
                                                const void* g2, const void* be2,
                                                u16* __restrict__ canon,
                                                const int* __restrict__ flag) {
    int f32 = *flag;
    int i = blockIdx.x * 256 + threadIdx.x;
    const void* src; int off;
    if      (i < 128)  { src = bl;   off = 0; }
    else if (i < 256)  { src = br;   off = 128; }
    else if (i < 384)  { src = att;  off = 256; }
    else if (i < 512)  { src = bgat; off = 384; }
    else if (i < 2560) { src = b1;   off = 512; }
    else if (i < 2688) { src = b2;   off = 2560; }
    else if (i < 2816) { src = g1;   off = 2688; }
    else if (i < 2944) { src = be1;  off = 2816; }
    else if (i < 3072) { src = g2;   off = 2944; }
    else if (i < 3200) { src = be2;  off = 3072; }
    else return;
    int j = i - off;
    canon[i] = f32 ? cleanf(((const float*)src)[j]) : cleanu(((const u16*)src)[j]);
}

// -------- convert+sanitize+transpose weights [R][C] -> bf16 [C][R] --------
__global__ __launch_bounds__(256) void k_t2(const void* __restrict__ in,
                                            u16* __restrict__ out, int R, int Cc,
                                            const int* __restrict__ flag) {
    int f32 = *flag;
    int i = blockIdx.x * 256 + threadIdx.x;
    if (i < R * Cc) {
        int r = i / Cc, c = i - r * Cc;
        u16 v = f32 ? cleanf(((const float*)in)[i]) : cleanu(((const u16*)in)[i]);
        out[c * R + r] = v;
    }
}

// -------- CSR of the shared 7000-edge graph (dst-indexed); int32/int64 auto --------
__global__ __launch_bounds__(1024) void k_csr(const int* __restrict__ ew,
                                              int* __restrict__ row_off,
                                              int* __restrict__ col) {
    __shared__ int cnt[NNODE];
    __shared__ int offs[NNODE + 1];
    __shared__ int cur[NNODE];
    __shared__ int flag;
    int tid = threadIdx.x;
    if (tid == 0) flag = 0;
    for (int i = tid; i < NNODE; i += 1024) cnt[i] = 0;
    __syncthreads();
    int f = 0;
    for (int j = tid; j < EE; j += 1024) f |= ew[2 * j + 1];
    if (f) atomicOr(&flag, 1);
    __syncthreads();
    bool is32 = (flag != 0);
    for (int e = tid; e < EE; e += 1024) {
        int dst = is32 ? ew[EE + e] : ew[2 * EE + 2 * e];
        if ((unsigned)dst < NNODE) atomicAdd(&cnt[dst], 1);
    }
    __syncthreads();
    if (tid == 0) {
        int run = 0;
        for (int i = 0; i < NNODE; ++i) { offs[i] = run; run += cnt[i]; }
        offs[NNODE] = run;
    }
    __syncthreads();
    for (int i = tid; i < NNODE; i += 1024) cur[i] = offs[i];
    __syncthreads();
    for (int e = tid; e < EE; e += 1024) {
        int src = is32 ? ew[e] : ew[2 * e];
        int dst = is32 ? ew[EE + e] : ew[2 * EE + 2 * e];
        if ((unsigned)dst < NNODE && (unsigned)src < NNODE) {
            int p = atomicAdd(&cur[dst], 1);
            if (p < EE) col[p] = src;
        }
    }
    __syncthreads();
    for (int i = tid; i <= NNODE; i += 1024) row_off[i] = offs[i];
}

// -------- x_l / x_r: [TN,128] @ [128,256] via MFMA --------
__global__ __launch_bounds__(256) void k_linlr(const void* __restrict__ xraw,
                                               const u16* __restrict__ wlrT,  // [256][128]
                                               const u16* __restrict__ canon,
                                               u16* __restrict__ xl, u16* __restrict__ xr,
                                               const int* __restrict__ flag) {
    __shared__ __align__(16) u16 a_tile[64 * 136];
    int f32 = *flag;
    int tid = threadIdx.x;
    int m0 = blockIdx.x * 64;
    for (int it = 0; it < 4; ++it) {
        int idx = it * 256 + tid;
        int row = idx >> 4, cc = idx & 15;
        int gm = m0 + row;
        u16 tmp[8];
#pragma unroll
        for (int j = 0; j < 8; ++j) tmp[j] = 0;
        if (gm < TN) {
            size_t base = (size_t)gm * DD + cc * 8;
            if (f32) {
                float4 v0 = *(const float4*)((const float*)xraw + base);
                float4 v1 = *(const float4*)((const float*)xraw + base + 4);
                tmp[0] = cleanf(v0.x); tmp[1] = cleanf(v0.y);
                tmp[2] = cleanf(v0.z); tmp[3] = cleanf(v0.w);
                tmp[4] = cleanf(v1.x); tmp[5] = cleanf(v1.y);
                tmp[6] = cleanf(v1.z); tmp[7] = cleanf(v1.w);
            } else {
                uint4 v = *(const uint4*)((const u16*)xraw + base);
                unsigned wv[4] = {v.x, v.y, v.z, v.w};
#pragma unroll
                for (int j = 0; j < 8; ++j)
                    tmp[j] = cleanu((u16)((wv[j >> 1] >> ((j & 1) * 16)) & 0xFFFFu));
            }
        }
        uint4 o;
        o.x = (unsigned)tmp[0] | ((unsigned)tmp[1] << 16);
        o.y = (unsigned)tmp[2] | ((unsigned)tmp[3] << 16);
        o.z = (unsigned)tmp[4] | ((unsigned)tmp[5] << 16);
        o.w = (unsigned)tmp[6] | ((unsigned)tmp[7] << 16);
        *(uint4*)(a_tile + row * 136 + cc * 8) = o;
    }
    __syncthreads();
    int wave = tid >> 6, lane = tid & 63, n16 = lane & 15, q = lane >> 4;
    f32x4 acc[16];
#pragma unroll
    for (int t = 0; t < 16; ++t) acc[t] = (f32x4){0, 0, 0, 0};
    const u16* arow = a_tile + (16 * wave + n16) * 136;
#pragma unroll
    for (int ks = 0; ks < 4; ++ks) {
        bf16x8 a = *(const bf16x8*)(arow + ks * 32 + q * 8);
#pragma unroll
        for (int t = 0; t < 16; ++t) {
            bf16x8 b = *(const bf16x8*)(wlrT + ((size_t)(t * 16 + n16)) * DD + ks * 32 + q * 8);
            acc[t] = __builtin_amdgcn_mfma_f32_16x16x32_bf16(a, b, acc[t], 0, 0, 0);
        }
    }
#pragma unroll
    for (int t = 0; t < 16; ++t) {
        int cc = (t & 7) * 16 + n16;
        float bias = bf2f(canon[(t < 8 ? 0 : 128) + cc]);
        u16* dst = (t < 8 ? xl : xr);
#pragma unroll
        for (int reg = 0; reg < 4; ++reg) {
            int mrow = m0 + 16 * wave + 4 * q + reg;
            if (mrow < TN) dst[(size_t)mrow * DD + cc] = f2bf(acc[t][reg] + bias);
        }
    }
}

// -------- 16-lane segment sum --------
__device__ __forceinline__ float segsum16(float p) {
    p += __shfl_xor(p, 1, 16);
    p += __shfl_xor(p, 2, 16);
    p += __shfl_xor(p, 4, 16);
    p += __shfl_xor(p, 8, 16);
    return p;
}

// -------- GATv2: single-pass online softmax + residual + LN1 --------
__global__ __launch_bounds__(256) void k_gat(const void* __restrict__ xraw,
                                             const u16* __restrict__ xl,
                                             const u16* xr,
                                             const u16* __restrict__ canon,
                                             const int* __restrict__ row_off,
                                             const int* __restrict__ col,
                                             u16* h1,
                                             const int* __restrict__ flag) {
    int f32 = *flag;
    int tid = threadIdx.x;
    int local = tid >> 7;
    int d = tid & 127;
    int g = blockIdx.x * 2 + local;            // TN even
    int bt = g / NNODE;
    int i = g - bt * NNODE;
    size_t gbase = (size_t)g * DD;
    size_t nbase = (size_t)bt * NNODE;
    float xr_d = bf2f(xr[gbase + d]);
    float att_d = bf2f(canon[256 + d]);
    float xl_self = bf2f(xl[gbase + d]);
    int r0 = row_off[i], r1 = row_off[i + 1];
    // online softmax: start with the self-loop
    float t0 = xl_self + xr_d; t0 = t0 > 0.f ? t0 : 0.2f * t0;
    float m = segsum16(t0 * att_d);
    float denom = 1.f;
    float acc = xl_self;
    for (int e = r0; e < r1; ++e) {
        int j = col[e];
        if ((unsigned)j >= NNODE) continue;
        float xlj = bf2f(xl[(nbase + j) * DD + d]);
        float t = xlj + xr_d; t = t > 0.f ? t : 0.2f * t;
        float s = segsum16(t * att_d);
        float mn = fmaxf(m, s);
        float eo = __expf(m - mn);
        float en = __expf(s - mn);
        denom = denom * eo + en;
        acc = acc * eo + en * xlj;
        m = mn;
    }
    float pre = acc / denom + bf2f(canon[384 + d]) + loadx(xraw, gbase + d, f32);
    // LN1 across 128 channels (2 waves per node)
    float sum = pre, sq = pre * pre;
    for (int off = 32; off; off >>= 1) {
        sum += __shfl_xor(sum, off);
        sq  += __shfl_xor(sq, off);
    }
    __shared__ float part[2][2][2];
    int win = (tid >> 6) & 1;
    if ((tid & 63) == 0) { part[local][win][0] = sum; part[local][win][1] = sq; }
    __syncthreads();
    float ts = part[local][0][0] + part[local][1][0];
    float tq = part[local][0][1] + part[local][1][1];
    float mu = ts * (1.0f / 128.0f);
    float var = fmaxf(tq * (1.0f / 128.0f) - mu * mu, 0.f);
    float rs = rsqrtf(var + 1e-5f);
    float hv = (pre - mu) * rs * bf2f(canon[2688 + d]) + bf2f(canon[2816 + d]);
    h1[gbase + d] = f2bf(hv);
}

// -------- fused FFN + residual + LN2: async LDS weight staging --------
// M=64/block, wave = 16 rows. W1/W2 chunks staged with global_load_lds
// (direct DMA, no VGPRs); 16-B blocks XOR-swizzled (phys = blk ^ (row&7))
// so unpadded rows read conflict-free (2-way = free). s separate, padded.
// LDS = 16384 + 16384 + 9216 = 41984 B -> 3 blocks/CU.
__global__ __launch_bounds__(256, 3) void k_ffn(const u16* __restrict__ h1,
                                                const u16* __restrict__ w1T,  // [2048][128]
                                                const u16* __restrict__ w2T,  // [128][2048]
                                                const u16* __restrict__ canon,
                                                void* __restrict__ outraw,
                                                const int* __restrict__ flag) {
    __shared__ __align__(16) u16 w1b[64 * 128];   // chunk of W1, swizzled
    __shared__ __align__(16) u16 w2b[128 * 64];   // chunk of W2, swizzled
    __shared__ __align__(16) u16 s_t[64 * 72];    // s = relu(h@W1+b1), padded
    int f32 = *flag;
    int tid = threadIdx.x;
    int wave = tid >> 6, lane = tid & 63, n16 = lane & 15, q = lane >> 4;
    int m0 = blockIdx.x * 64;
    int swz = n16 & 7;                             // row-dependent block swizzle
    // A-fragments of h for this wave's 16 rows, registers all kernel
    bf16x8 af[4];
    {
        int gm = m0 + 16 * wave + n16;
#pragma unroll
        for (int ks = 0; ks < 4; ++ks) {
            if (gm < TN) {
                uint4 v = *(const uint4*)(h1 + (size_t)gm * DD + ks * 32 + q * 8);
                af[ks] = *(const bf16x8*)&v;
            } else {
                uint4 z = make_uint4(0, 0, 0, 0);
                af[ks] = *(const bf16x8*)&z;
            }
        }
    }
    f32x4 acc2[8];
#pragma unroll
    for (int t = 0; t < 8; ++t) acc2[t] = (f32x4){0, 0, 0, 0};
    // staging geometry (per wave, 4 issues each for W1 and W2):
    // W1 issue i: rows 16w+4i+(lane>>4), phys blk lane&15, logical = phys^ (r&7)
    int w1r[4], w1b_log[4];
#pragma unroll
    for (int i = 0; i < 4; ++i) {
        w1r[i] = 16 * wave + 4 * i + (lane >> 4);
        w1b_log[i] = (lane & 15) ^ (w1r[i] & 7);
    }
    // W2 issue i: rows 32w+8i+(lane>>3), phys blk lane&7
    int w2r[4], w2b_log[4];
#pragma unroll
    for (int i = 0; i < 4; ++i) {
        w2r[i] = 32 * wave + 8 * i + (lane >> 3);
        w2b_log[i] = (lane & 7) ^ (w2r[i] & 7);
    }
    const u16* srow_r = s_t + (16 * wave + n16) * 72;
    u16* srow_w = s_t + (16 * wave + 4 * q) * 72;
    for (int ch = 0; ch < 32; ++ch) {
        int f0 = ch * 64;
        __syncthreads();   // prior chunk's w1b/w2b/s consumers done
        // async stage W1 chunk [64 rows f0..f0+63][128] and W2 chunk [128][64]
#pragma unroll
        for (int i = 0; i < 4; ++i) {
            glb_u16* g1 = (glb_u16*)(w1T + (size_t)(f0 + w1r[i]) * DD + w1b_log[i] * 8);
            lds_u16* l1 = (lds_u16*)(w1b + (16 * wave + 4 * i) * 128);
            __builtin_amdgcn_global_load_lds((const __attribute__((address_space(1))) unsigned*)g1,
                                             (__attribute__((address_space(3))) unsigned*)l1,
                                             16, 0, 0);
        }
#pragma unroll
        for (int i = 0; i < 4; ++i) {
            glb_u16* g2 = (glb_u16*)(w2T + (size_t)w2r[i] * FFDIM + f0 + w2b_log[i] * 8);
            lds_u16* l2 = (lds_u16*)(w2b + (32 * wave + 8 * i) * 64);
            __builtin_amdgcn_global_load_lds((const __attribute__((address_space(1))) unsigned*)g2,
                                             (__attribute__((address_space(3))) unsigned*)l2,
                                             16, 0, 0);
        }
        __syncthreads();   // drains vmcnt: staged chunk visible
        // GEMM1: s = relu(h @ W1chunk + b1), t-sequential (low VGPR)
#pragma unroll
        for (int t = 0; t < 4; ++t) {
            f32x4 a1 = (f32x4){0, 0, 0, 0};
#pragma unroll
            for (int ks = 0; ks < 4; ++ks) {
                bf16x8 b = *(const bf16x8*)(w1b + (t * 16 + n16) * 128 + (((ks * 4 + q) ^ swz) * 8));
                a1 = __builtin_amdgcn_mfma_f32_16x16x32_bf16(af[ks], b, a1, 0, 0, 0);
            }
            float bb = bf2f(canon[512 + f0 + t * 16 + n16]);
#pragma unroll
            for (int reg = 0; reg < 4; ++reg) {
                float v = a1[reg] + bb;
                v = v > 0.f ? v : 0.f;
                srow_w[reg * 72 + t * 16 + n16] = f2bf(v);
            }
        }
        asm volatile("" ::: "memory");
        // GEMM2: acc2 += s @ W2chunk (s rows wave-private; per-wave DS order ok)
#pragma unroll
        for (int ks2 = 0; ks2 < 2; ++ks2) {
            bf16x8 a2 = *(const bf16x8*)(srow_r + ks2 * 32 + q * 8);
#pragma unroll
            for (int t = 0; t < 8; ++t) {
                bf16x8 b = *(const bf16x8*)(w2b + (t * 16 + n16) * 64 + (((ks2 * 4 + q) ^ swz) * 8));
                acc2[t] = __builtin_amdgcn_mfma_f32_16x16x32_bf16(a2, b, acc2[t], 0, 0, 0);
            }
        }
        asm volatile("" ::: "memory");
    }
    // epilogue: +b2 +residual, LN2 via 16-lane shuffles (row lives in one quad)
    float b2v[8], g2v[8], e2v[8];
#pragma unroll
    for (int t = 0; t < 8; ++t) {
        int col = t * 16 + n16;
        b2v[t] = bf2f(canon[2560 + col]);
        g2v[t] = bf2f(canon[2944 + col]);
        e2v[t] = bf2f(canon[3072 + col]);
    }
#pragma unroll
    for (int reg = 0; reg < 4; ++reg) {
        int row = 16 * wave + 4 * q + reg;
        int gm = m0 + row;
        bool ok = gm < TN;
        size_t gb = (size_t)(ok ? gm : 0) * DD;
        float v[8]; float s1 = 0.f, s2 = 0.f;
#pragma unroll
        for (int t = 0; t < 8; ++t) {
            float hres = bf2f(h1[gb + t * 16 + n16]);
            v[t] = acc2[t][reg] + b2v[t] + hres;
            s1 += v[t]; s2 += v[t] * v[t];
        }
        s1 = segsum16(s1);
        s2 = segsum16(s2);
        float mu = s1 * (1.f / 128.f);
        float var = fmaxf(s2 * (1.f / 128.f) - mu * mu, 0.f);
        float rs = rsqrtf(var + 1e-5f);
        if (ok) {
#pragma unroll
            for (int t = 0; t < 8; ++t) {
                float r = (v[t] - mu) * rs * g2v[t] + e2v[t];
                if (f32) ((float*)outraw)[gb + t * 16 + n16] = r;
                else     ((u16*)outraw)[gb + t * 16 + n16] = f2bf(r);
            }
        }
    }
}

extern "C" void kernel_launch(void* const* d_in, const int* in_sizes, int n_in,
                              void* d_out, int out_size, void* d_ws, size_t ws_size,
                              hipStream_t stream) {
    const void* x    = d_in[0];
    const int* eidx  = (const int*)d_in[1];
    const void* Wl   = d_in[2];
    const void* bl   = d_in[3];
    const void* Wr   = d_in[4];
    const void* br   = d_in[5];
    const void* att  = d_in[6];
    const void* bgat = d_in[7];
    const void* W1   = d_in[8];
    const void* b1   = d_in[9];
    const void* W2   = d_in[10];
    const void* b2   = d_in[11];
    const void* g1   = d_in[12];
    const void* be1  = d_in[13];
    const void* g2   = d_in[14];
    const void* be2  = d_in[15];

    // ws layout (bytes): flag@0, rowoff@4096, colw@8192, canon@36864,
    // wlrT@65536, w1T@131072, w2T@655360, xl@1179648, xr/h1@22880256
    char* ws = (char*)d_ws;
    int* flag   = (int*)(ws);
    int* rowoff = (int*)(ws + 4096);
    int* colw   = (int*)(ws + 8192);
    u16* canon  = (u16*)(ws + 36864);
    u16* wlrT   = (u16*)(ws + 65536);
    u16* w1T    = (u16*)(ws + 131072);
    u16* w2T    = (u16*)(ws + 655360);
    u16* xl     = (u16*)(ws + 1179648);
    u16* xr     = (u16*)(ws + 22880256);
    u16* h1     = xr;   // k_gat reads xr[addr] before writing h1[addr]

    k_detect<<<1, 256, 0, stream>>>((const unsigned*)x, flag);
    k_params<<<13, 256, 0, stream>>>(bl, br, att, bgat, b1, b2, g1, be1, g2, be2,
                                     canon, flag);
    k_t2<<<64, 256, 0, stream>>>(Wl, wlrT, 128, 128, flag);
    k_t2<<<64, 256, 0, stream>>>(Wr, wlrT + 16384, 128, 128, flag);
    k_t2<<<1024, 256, 0, stream>>>(W1, w1T, 128, 2048, flag);
    k_t2<<<1024, 256, 0, stream>>>(W2, w2T, 2048, 128, flag);
    k_csr<<<1, 1024, 0, stream>>>(eidx, rowoff, colw);
    k_linlr<<<(TN + 63) / 64, 256, 0, stream>>>(x, wlrT, canon, xl, xr, flag);
    k_gat<<<TN / 2, 256, 0, stream>>>(x, xl, xr, canon, rowoff, colw, h1, flag);
    k_ffn<<<(TN + 63) / 64, 256, 0, stream>>>(h1, w1T, w2T, canon, d_out, flag);
}

// Round 8
// 438.953 us; speedup vs baseline: 1.9220x; 1.2250x over previous
//
#include <hip/hip_runtime.h>
#include <stdint.h>

typedef unsigned short u16;

#define TN    84768      // B*T*N = 8*12*883
#define NNODE 883
#define DD    128
#define EE    7000
#define FFDIM 2048

typedef short bf16x8 __attribute__((ext_vector_type(8)));
typedef float f32x4  __attribute__((ext_vector_type(4)));
typedef __attribute__((address_space(3))) u16 lds_u16;
typedef const __attribute__((address_space(1))) u16 glb_u16;

__device__ __forceinline__ float bf2f(u16 u) {
    unsigned int x = ((unsigned int)u) << 16;
    return __uint_as_float(x);
}
__device__ __forceinline__ u16 f2bf(float f) {
    unsigned int x = __float_as_uint(f);
    x += 0x7FFFu + ((x >> 16) & 1u);   // round-to-nearest-even
    return (u16)(x >> 16);
}
// sanitize: any Inf/NaN bit pattern -> 0
__device__ __forceinline__ u16 cleanu(u16 u) {
    return (((u >> 7) & 0xFF) == 0xFF) ? (u16)0 : u;
}
__device__ __forceinline__ u16 cleanf(float f) {
    unsigned b = __float_as_uint(f);
    if (((b >> 23) & 0xFF) == 0xFF) return 0;
    return cleanu(f2bf(f));
}
__device__ __forceinline__ float loadx(const void* p, size_t i, int f32) {
    if (f32) {
        float v = ((const float*)p)[i];
        unsigned b = __float_as_uint(v);
        if (((b >> 23) & 0xFF) == 0xFF) v = 0.f;
        return v;
    }
    return bf2f(cleanu(((const u16*)p)[i]));
}

// -------- dtype detect: bf16-packed vs fp32 --------
__global__ __launch_bounds__(256) void k_detect(const unsigned* __restrict__ x,
                                                int* __restrict__ flag) {
    __shared__ int cnt;
    if (threadIdx.x == 0) cnt = 0;
    __syncthreads();
    unsigned w = x[threadIdx.x];
    unsigned e = (w >> 7) & 0xFF;
    int ok = (e >= 96 && e <= 144) || ((w & 0xFFFFu) == 0);
    atomicAdd(&cnt, ok);
    __syncthreads();
    if (threadIdx.x == 0) flag[0] = (cnt < 200) ? 1 : 0;   // 1 = fp32
}

// -------- fused prep: all weight transposes + param sanitize --------
// ranges (elements): [0,16384) Wl->wlrT; [16384,32768) Wr->wlrT+16384;
// [32768,294912) W1(128x2048)->w1T; [294912,557056) W2(2048x128)->w2T;
// [557056,560256) params->canon
__global__ __launch_bounds__(256) void k_prep(const void* Wl, const void* Wr,
                                              const void* W1, const void* W2,
                                              const void* bl, const void* br,
                                              const void* att, const void* bgat,
                                              const void* b1, const void* b2,
                                              const void* g1, const void* be1,
                                              const void* g2, const void* be2,
                                              u16* __restrict__ wlrT,
                                              u16* __restrict__ w1T,
                                              u16* __restrict__ w2T,
                                              u16* __restrict__ canon,
                                              const int* __restrict__ flag) {
    int f32 = *flag;
    int i = blockIdx.x * 256 + threadIdx.x;
    if (i < 16384) {
        int r = i >> 7, c = i & 127;
        u16 v = f32 ? cleanf(((const float*)Wl)[i]) : cleanu(((const u16*)Wl)[i]);
        wlrT[c * 128 + r] = v;
    } else if (i < 32768) {
        int idx = i - 16384;
        int r = idx >> 7, c = idx & 127;
        u16 v = f32 ? cleanf(((const float*)Wr)[idx]) : cleanu(((const u16*)Wr)[idx]);
        wlrT[16384 + c * 128 + r] = v;
    } else if (i < 294912) {
        int idx = i - 32768;
        int r = idx >> 11, c = idx & 2047;    // [128][2048]
        u16 v = f32 ? cleanf(((const float*)W1)[idx]) : cleanu(((const u16*)W1)[idx]);
        w1T[c * 128 + r] = v;
    } else if (i < 557056) {
        int idx = i - 294912;
        int r = idx >> 7, c = idx & 127;      // [2048][128]
        u16 v = f32 ? cleanf(((const float*)W2)[idx]) : cleanu(((const u16*)W2)[idx]);
        w2T[c * 2048 + r] = v;
    } else if (i < 560256) {
        int p = i - 557056;
        const void* src; int off;
        if      (p < 128)  { src = bl;   off = 0; }
        else if (p < 256)  { src = br;   off = 128; }
        else if (p < 384)  { src = att;  off = 256; }
        else if (p < 512)  { src = bgat; off = 384; }
        else if (p < 2560) { src = b1;   off = 512; }
        else if (p < 2688) { src = b2;   off = 2560; }
        else if (p < 2816) { src = g1;   off = 2688; }
        else if (p < 2944) { src = be1;  off = 2816; }
        else if (p < 3072) { src = g2;   off = 2944; }
        else               { src = be2;  off = 3072; }
        int j = p - off;
        canon[p] = f32 ? cleanf(((const float*)src)[j]) : cleanu(((const u16*)src)[j]);
    }
}

// -------- CSR of the shared 7000-edge graph (dst-indexed); int32/int64 auto --------
__global__ __launch_bounds__(1024) void k_csr(const int* __restrict__ ew,
                                              int* __restrict__ row_off,
                                              int* __restrict__ col) {
    __shared__ int cnt[NNODE];
    __shared__ int offs[NNODE + 1];
    __shared__ int cur[NNODE];
    __shared__ int flag;
    int tid = threadIdx.x;
    if (tid == 0) flag = 0;
    for (int i = tid; i < NNODE; i += 1024) cnt[i] = 0;
    __syncthreads();
    int f = 0;
    for (int j = tid; j < EE; j += 1024) f |= ew[2 * j + 1];
    if (f) atomicOr(&flag, 1);
    __syncthreads();
    bool is32 = (flag != 0);
    for (int e = tid; e < EE; e += 1024) {
        int dst = is32 ? ew[EE + e] : ew[2 * EE + 2 * e];
        if ((unsigned)dst < NNODE) atomicAdd(&cnt[dst], 1);
    }
    __syncthreads();
    if (tid == 0) {
        int run = 0;
        for (int i = 0; i < NNODE; ++i) { offs[i] = run; run += cnt[i]; }
        offs[NNODE] = run;
    }
    __syncthreads();
    for (int i = tid; i < NNODE; i += 1024) cur[i] = offs[i];
    __syncthreads();
    for (int e = tid; e < EE; e += 1024) {
        int src = is32 ? ew[e] : ew[2 * e];
        int dst = is32 ? ew[EE + e] : ew[2 * EE + 2 * e];
        if ((unsigned)dst < NNODE && (unsigned)src < NNODE) {
            int p = atomicAdd(&cur[dst], 1);
            if (p < EE) col[p] = src;
        }
    }
    __syncthreads();
    for (int i = tid; i <= NNODE; i += 1024) row_off[i] = offs[i];
}

// -------- x_l / x_r: [TN,128] @ [128,256] via MFMA --------
__global__ __launch_bounds__(256) void k_linlr(const void* __restrict__ xraw,
                                               const u16* __restrict__ wlrT,  // [256][128]
                                               const u16* __restrict__ canon,
                                               u16* __restrict__ xl, u16* __restrict__ xr,
                                               const int* __restrict__ flag) {
    __shared__ __align__(16) u16 a_tile[64 * 136];
    int f32 = *flag;
    int tid = threadIdx.x;
    int m0 = blockIdx.x * 64;
    for (int it = 0; it < 4; ++it) {
        int idx = it * 256 + tid;
        int row = idx >> 4, cc = idx & 15;
        int gm = m0 + row;
        u16 tmp[8];
#pragma unroll
        for (int j = 0; j < 8; ++j) tmp[j] = 0;
        if (gm < TN) {
            size_t base = (size_t)gm * DD + cc * 8;
            if (f32) {
                float4 v0 = *(const float4*)((const float*)xraw + base);
                float4 v1 = *(const float4*)((const float*)xraw + base + 4);
                tmp[0] = cleanf(v0.x); tmp[1] = cleanf(v0.y);
                tmp[2] = cleanf(v0.z); tmp[3] = cleanf(v0.w);
                tmp[4] = cleanf(v1.x); tmp[5] = cleanf(v1.y);
                tmp[6] = cleanf(v1.z); tmp[7] = cleanf(v1.w);
            } else {
                uint4 v = *(const uint4*)((const u16*)xraw + base);
                unsigned wv[4] = {v.x, v.y, v.z, v.w};
#pragma unroll
                for (int j = 0; j < 8; ++j)
                    tmp[j] = cleanu((u16)((wv[j >> 1] >> ((j & 1) * 16)) & 0xFFFFu));
            }
        }
        uint4 o;
        o.x = (unsigned)tmp[0] | ((unsigned)tmp[1] << 16);
        o.y = (unsigned)tmp[2] | ((unsigned)tmp[3] << 16);
        o.z = (unsigned)tmp[4] | ((unsigned)tmp[5] << 16);
        o.w = (unsigned)tmp[6] | ((unsigned)tmp[7] << 16);
        *(uint4*)(a_tile + row * 136 + cc * 8) = o;
    }
    __syncthreads();
    int wave = tid >> 6, lane = tid & 63, n16 = lane & 15, q = lane >> 4;
    f32x4 acc[16];
#pragma unroll
    for (int t = 0; t < 16; ++t) acc[t] = (f32x4){0, 0, 0, 0};
    const u16* arow = a_tile + (16 * wave + n16) * 136;
#pragma unroll
    for (int ks = 0; ks < 4; ++ks) {
        bf16x8 a = *(const bf16x8*)(arow + ks * 32 + q * 8);
#pragma unroll
        for (int t = 0; t < 16; ++t) {
            bf16x8 b = *(const bf16x8*)(wlrT + ((size_t)(t * 16 + n16)) * DD + ks * 32 + q * 8);
            acc[t] = __builtin_amdgcn_mfma_f32_16x16x32_bf16(a, b, acc[t], 0, 0, 0);
        }
    }
#pragma unroll
    for (int t = 0; t < 16; ++t) {
        int cc = (t & 7) * 16 + n16;
        float bias = bf2f(canon[(t < 8 ? 0 : 128) + cc]);
        u16* dst = (t < 8 ? xl : xr);
#pragma unroll
        for (int reg = 0; reg < 4; ++reg) {
            int mrow = m0 + 16 * wave + 4 * q + reg;
            if (mrow < TN) dst[(size_t)mrow * DD + cc] = f2bf(acc[t][reg] + bias);
        }
    }
}

// -------- 16-lane segment sum --------
__device__ __forceinline__ float segsum16(float p) {
    p += __shfl_xor(p, 1, 16);
    p += __shfl_xor(p, 2, 16);
    p += __shfl_xor(p, 4, 16);
    p += __shfl_xor(p, 8, 16);
    return p;
}

// -------- GATv2: 1 wave/node, 2 packed channels/lane, no-max softmax --------
// Scores here are tiny (inputs ~N(0,0.6), att ~0.05); clamp +-30 makes exp
// overflow-proof without max subtraction (ratio unchanged). Head dot = 8
// lanes (16 channels, 2/lane) via width-8 shuffles. Edge row address is
// scalarized (readfirstlane) -> zero per-lane addressing VALU in the loop.
__global__ __launch_bounds__(256) void k_gat(const void* __restrict__ xraw,
                                             const u16* __restrict__ xl,
                                             const u16* xr,
                                             const u16* __restrict__ canon,
                                             const int* __restrict__ row_off,
                                             const int* __restrict__ col,
                                             u16* h1,
                                             const int* __restrict__ flag) {
    int f32 = *flag;
    int tid = threadIdx.x;
    int wave = tid >> 6, lane = tid & 63;
    int g = blockIdx.x * 4 + wave;             // TN % 4 == 0
    int bt = g / NNODE;
    int i = g - bt * NNODE;
    size_t gbase = (size_t)g * DD;
    const u16* xlrow0 = xl + (size_t)bt * NNODE * DD;
    int c2 = lane * 2;
    unsigned uxr = *(const unsigned*)(xr + gbase + c2);
    float xr0 = __uint_as_float(uxr << 16);
    float xr1 = __uint_as_float(uxr & 0xFFFF0000u);
    unsigned uat = *(const unsigned*)(canon + 256 + c2);
    float at0 = __uint_as_float(uat << 16);
    float at1 = __uint_as_float(uat & 0xFFFF0000u);
    unsigned uxs = *(const unsigned*)(xl + gbase + c2);
    float xs0 = __uint_as_float(uxs << 16);
    float xs1 = __uint_as_float(uxs & 0xFFFF0000u);
    // self-loop
    float t0 = xs0 + xr0, t1 = xs1 + xr1;
    t0 = fmaxf(t0, 0.2f * t0); t1 = fmaxf(t1, 0.2f * t1);
    float p = t0 * at0 + t1 * at1;
    p += __shfl_xor(p, 1, 8);
    p += __shfl_xor(p, 2, 8);
    p += __shfl_xor(p, 4, 8);
    p = fminf(fmaxf(p, -30.f), 30.f);
    float w = __expf(p);
    float denom = w;
    float a0 = w * xs0, a1 = w * xs1;
    int r0 = row_off[i], r1 = row_off[i + 1];
    for (int e = r0; e < r1; ++e) {
        int j = __builtin_amdgcn_readfirstlane(col[e]);
        if ((unsigned)j >= NNODE) continue;
        unsigned uj = *(const unsigned*)(xlrow0 + (size_t)j * DD + c2);
        float x0 = __uint_as_float(uj << 16);
        float x1 = __uint_as_float(uj & 0xFFFF0000u);
        float u0 = x0 + xr0, u1 = x1 + xr1;
        u0 = fmaxf(u0, 0.2f * u0); u1 = fmaxf(u1, 0.2f * u1);
        float q = u0 * at0 + u1 * at1;
        q += __shfl_xor(q, 1, 8);
        q += __shfl_xor(q, 2, 8);
        q += __shfl_xor(q, 4, 8);
        q = fminf(fmaxf(q, -30.f), 30.f);
        float ww = __expf(q);
        denom += ww;
        a0 += ww * x0;
        a1 += ww * x1;
    }
    float inv = 1.f / denom;
    unsigned ubg = *(const unsigned*)(canon + 384 + c2);
    float res0, res1;
    if (f32) {
        float2 rr = *(const float2*)((const float*)xraw + gbase + c2);
        unsigned b0 = __float_as_uint(rr.x), b1 = __float_as_uint(rr.y);
        res0 = (((b0 >> 23) & 0xFF) == 0xFF) ? 0.f : rr.x;
        res1 = (((b1 >> 23) & 0xFF) == 0xFF) ? 0.f : rr.y;
    } else {
        unsigned ux = *(const unsigned*)((const u16*)xraw + gbase + c2);
        res0 = bf2f(cleanu((u16)(ux & 0xFFFFu)));
        res1 = bf2f(cleanu((u16)(ux >> 16)));
    }
    float pre0 = a0 * inv + __uint_as_float(ubg << 16) + res0;
    float pre1 = a1 * inv + __uint_as_float(ubg & 0xFFFF0000u) + res1;
    // LN1 wave-local across 128 channels
    float sum = pre0 + pre1, sq = pre0 * pre0 + pre1 * pre1;
    for (int off = 32; off; off >>= 1) {
        sum += __shfl_xor(sum, off);
        sq  += __shfl_xor(sq, off);
    }
    float mu = sum * (1.0f / 128.0f);
    float var = fmaxf(sq * (1.0f / 128.0f) - mu * mu, 0.f);
    float rs = rsqrtf(var + 1e-5f);
    unsigned ug = *(const unsigned*)(canon + 2688 + c2);
    unsigned ub = *(const unsigned*)(canon + 2816 + c2);
    float h0 = (pre0 - mu) * rs * __uint_as_float(ug << 16) + __uint_as_float(ub << 16);
    float h1v = (pre1 - mu) * rs * __uint_as_float(ug & 0xFFFF0000u) + __uint_as_float(ub & 0xFFFF0000u);
    unsigned out = (unsigned)f2bf(h0) | ((unsigned)f2bf(h1v) << 16);
    *(unsigned*)(h1 + gbase + c2) = out;
}

// -------- fused FFN + residual + LN2: async LDS weight staging --------
// M=64/block, wave = 16 rows. W1/W2 chunks staged with global_load_lds
// (direct DMA, no VGPRs); 16-B blocks XOR-swizzled (phys = blk ^ (row&7)).
// LDS = 16384 + 16384 + 9216 = 41984 B -> 3 blocks/CU.
__global__ __launch_bounds__(256, 3) void k_ffn(const u16* __restrict__ h1,
                                                const u16* __restrict__ w1T,  // [2048][128]
                                                const u16* __restrict__ w2T,  // [128][2048]
                                                const u16* __restrict__ canon,
                                                void* __restrict__ outraw,
                                                const int* __restrict__ flag) {
    __shared__ __align__(16) u16 w1b[64 * 128];   // chunk of W1, swizzled
    __shared__ __align__(16) u16 w2b[128 * 64];   // chunk of W2, swizzled
    __shared__ __align__(16) u16 s_t[64 * 72];    // s = relu(h@W1+b1), padded
    int f32 = *flag;
    int tid = threadIdx.x;
    int wave = tid >> 6, lane = tid & 63, n16 = lane & 15, q = lane >> 4;
    int m0 = blockIdx.x * 64;
    int swz = n16 & 7;
    bf16x8 af[4];
    {
        int gm = m0 + 16 * wave + n16;
#pragma unroll
        for (int ks = 0; ks < 4; ++ks) {
            if (gm < TN) {
                uint4 v = *(const uint4*)(h1 + (size_t)gm * DD + ks * 32 + q * 8);
                af[ks] = *(const bf16x8*)&v;
            } else {
                uint4 z = make_uint4(0, 0, 0, 0);
                af[ks] = *(const bf16x8*)&z;
            }
        }
    }
    f32x4 acc2[8];
#pragma unroll
    for (int t = 0; t < 8; ++t) acc2[t] = (f32x4){0, 0, 0, 0};
    int w1r[4], w1b_log[4];
#pragma unroll
    for (int i = 0; i < 4; ++i) {
        w1r[i] = 16 * wave + 4 * i + (lane >> 4);
        w1b_log[i] = (lane & 15) ^ (w1r[i] & 7);
    }
    int w2r[4], w2b_log[4];
#pragma unroll
    for (int i = 0; i < 4; ++i) {
        w2r[i] = 32 * wave + 8 * i + (lane >> 3);
        w2b_log[i] = (lane & 7) ^ (w2r[i] & 7);
    }
    const u16* srow_r = s_t + (16 * wave + n16) * 72;
    u16* srow_w = s_t + (16 * wave + 4 * q) * 72;
    for (int ch = 0; ch < 32; ++ch) {
        int f0 = ch * 64;
        __syncthreads();
#pragma unroll
        for (int i = 0; i < 4; ++i) {
            glb_u16* g1 = (glb_u16*)(w1T + (size_t)(f0 + w1r[i]) * DD + w1b_log[i] * 8);
            lds_u16* l1 = (lds_u16*)(w1b + (16 * wave + 4 * i) * 128);
            __builtin_amdgcn_global_load_lds((const __attribute__((address_space(1))) unsigned*)g1,
                                             (__attribute__((address_space(3))) unsigned*)l1,
                                             16, 0, 0);
        }
#pragma unroll
        for (int i = 0; i < 4; ++i) {
            glb_u16* g2 = (glb_u16*)(w2T + (size_t)w2r[i] * FFDIM + f0 + w2b_log[i] * 8);
            lds_u16* l2 = (lds_u16*)(w2b + (32 * wave + 8 * i) * 64);
            __builtin_amdgcn_global_load_lds((const __attribute__((address_space(1))) unsigned*)g2,
                                             (__attribute__((address_space(3))) unsigned*)l2,
                                             16, 0, 0);
        }
        __syncthreads();
#pragma unroll
        for (int t = 0; t < 4; ++t) {
            f32x4 a1 = (f32x4){0, 0, 0, 0};
#pragma unroll
            for (int ks = 0; ks < 4; ++ks) {
                bf16x8 b = *(const bf16x8*)(w1b + (t * 16 + n16) * 128 + (((ks * 4 + q) ^ swz) * 8));
                a1 = __builtin_amdgcn_mfma_f32_16x16x32_bf16(af[ks], b, a1, 0, 0, 0);
            }
            float bb = bf2f(canon[512 + f0 + t * 16 + n16]);
#pragma unroll
            for (int reg = 0; reg < 4; ++reg) {
                float v = a1[reg] + bb;
                v = v > 0.f ? v : 0.f;
                srow_w[reg * 72 + t * 16 + n16] = f2bf(v);
            }
        }
        asm volatile("" ::: "memory");
#pragma unroll
        for (int ks2 = 0; ks2 < 2; ++ks2) {
            bf16x8 a2 = *(const bf16x8*)(srow_r + ks2 * 32 + q * 8);
#pragma unroll
            for (int t = 0; t < 8; ++t) {
                bf16x8 b = *(const bf16x8*)(w2b + (t * 16 + n16) * 64 + (((ks2 * 4 + q) ^ swz) * 8));
                acc2[t] = __builtin_amdgcn_mfma_f32_16x16x32_bf16(a2, b, acc2[t], 0, 0, 0);
            }
        }
        asm volatile("" ::: "memory");
    }
    float b2v[8], g2v[8], e2v[8];
#pragma unroll
    for (int t = 0; t < 8; ++t) {
        int col = t * 16 + n16;
        b2v[t] = bf2f(canon[2560 + col]);
        g2v[t] = bf2f(canon[2944 + col]);
        e2v[t] = bf2f(canon[3072 + col]);
    }
#pragma unroll
    for (int reg = 0; reg < 4; ++reg) {
        int row = 16 * wave + 4 * q + reg;
        int gm = m0 + row;
        bool ok = gm < TN;
        size_t gb = (size_t)(ok ? gm : 0) * DD;
        float v[8]; float s1 = 0.f, s2 = 0.f;
#pragma unroll
        for (int t = 0; t < 8; ++t) {
            float hres = bf2f(h1[gb + t * 16 + n16]);
            v[t] = acc2[t][reg] + b2v[t] + hres;
            s1 += v[t]; s2 += v[t] * v[t];
        }
        s1 = segsum16(s1);
        s2 = segsum16(s2);
        float mu = s1 * (1.f / 128.f);
        float var = fmaxf(s2 * (1.f / 128.f) - mu * mu, 0.f);
        float rs = rsqrtf(var + 1e-5f);
        if (ok) {
#pragma unroll
            for (int t = 0; t < 8; ++t) {
                float r = (v[t] - mu) * rs * g2v[t] + e2v[t];
                if (f32) ((float*)outraw)[gb + t * 16 + n16] = r;
                else     ((u16*)outraw)[gb + t * 16 + n16] = f2bf(r);
            }
        }
    }
}

extern "C" void kernel_launch(void* const* d_in, const int* in_sizes, int n_in,
                              void* d_out, int out_size, void* d_ws, size_t ws_size,
                              hipStream_t stream) {
    const void* x    = d_in[0];
    const int* eidx  = (const int*)d_in[1];
    const void* Wl   = d_in[2];
    const void* bl   = d_in[3];
    const void* Wr   = d_in[4];
    const void* br   = d_in[5];
    const void* att  = d_in[6];
    const void* bgat = d_in[7];
    const void* W1   = d_in[8];
    const void* b1   = d_in[9];
    const void* W2   = d_in[10];
    const void* b2   = d_in[11];
    const void* g1   = d_in[12];
    const void* be1  = d_in[13];
    const void* g2   = d_in[14];
    const void* be2  = d_in[15];

    // ws layout (bytes): flag@0, rowoff@4096, colw@8192, canon@36864,
    // wlrT@65536, w1T@131072, w2T@655360, xl@1179648, xr/h1@22880256
    char* ws = (char*)d_ws;
    int* flag   = (int*)(ws);
    int* rowoff = (int*)(ws + 4096);
    int* colw   = (int*)(ws + 8192);
    u16* canon  = (u16*)(ws + 36864);
    u16* wlrT   = (u16*)(ws + 65536);
    u16* w1T    = (u16*)(ws + 131072);
    u16* w2T    = (u16*)(ws + 655360);
    u16* xl     = (u16*)(ws + 1179648);
    u16* xr     = (u16*)(ws + 22880256);
    u16* h1     = xr;   // k_gat reads xr[addr] before writing h1[addr]

    k_csr<<<1, 1024, 0, stream>>>(eidx, rowoff, colw);
    k_detect<<<1, 256, 0, stream>>>((const unsigned*)x, flag);
    k_prep<<<2189, 256, 0, stream>>>(Wl, Wr, W1, W2, bl, br, att, bgat, b1, b2,
                                     g1, be1, g2, be2, wlrT, w1T, w2T, canon, flag);
    k_linlr<<<(TN + 63) / 64, 256, 0, stream>>>(x, wlrT, canon, xl, xr, flag);
    k_gat<<<TN / 4, 256, 0, stream>>>(x, xl, xr, canon, rowoff, colw, h1, flag);
    k_ffn<<<(TN + 63) / 64, 256, 0, stream>>>(h1, w1T, w2T, canon, d_out, flag);
}

// Round 9
// 399.992 us; speedup vs baseline: 2.1092x; 1.0974x over previous
//
#include <hip/hip_runtime.h>
#include <stdint.h>

typedef unsigned short u16;

#define TN    84768      // B*T*N = 8*12*883
#define NNODE 883
#define DD    128
#define EE    7000
#define FFDIM 2048

typedef short bf16x8 __attribute__((ext_vector_type(8)));
typedef float f32x4  __attribute__((ext_vector_type(4)));
typedef __attribute__((address_space(3))) u16 lds_u16;
typedef const __attribute__((address_space(1))) u16 glb_u16;

__device__ __forceinline__ float bf2f(u16 u) {
    unsigned int x = ((unsigned int)u) << 16;
    return __uint_as_float(x);
}
__device__ __forceinline__ u16 f2bf(float f) {
    unsigned int x = __float_as_uint(f);
    x += 0x7FFFu + ((x >> 16) & 1u);   // round-to-nearest-even
    return (u16)(x >> 16);
}
// sanitize: any Inf/NaN bit pattern -> 0
__device__ __forceinline__ u16 cleanu(u16 u) {
    return (((u >> 7) & 0xFF) == 0xFF) ? (u16)0 : u;
}
__device__ __forceinline__ u16 cleanf(float f) {
    unsigned b = __float_as_uint(f);
    if (((b >> 23) & 0xFF) == 0xFF) return 0;
    return cleanu(f2bf(f));
}

// -------- dtype detect: bf16-packed vs fp32 --------
__global__ __launch_bounds__(256) void k_detect(const unsigned* __restrict__ x,
                                                int* __restrict__ flag) {
    __shared__ int cnt;
    if (threadIdx.x == 0) cnt = 0;
    __syncthreads();
    unsigned w = x[threadIdx.x];
    unsigned e = (w >> 7) & 0xFF;
    int ok = (e >= 96 && e <= 144) || ((w & 0xFFFFu) == 0);
    atomicAdd(&cnt, ok);
    __syncthreads();
    if (threadIdx.x == 0) flag[0] = (cnt < 200) ? 1 : 0;   // 1 = fp32
}

// -------- fused prep: all weight transposes + param sanitize --------
__global__ __launch_bounds__(256) void k_prep(const void* Wl, const void* Wr,
                                              const void* W1, const void* W2,
                                              const void* bl, const void* br,
                                              const void* att, const void* bgat,
                                              const void* b1, const void* b2,
                                              const void* g1, const void* be1,
                                              const void* g2, const void* be2,
                                              u16* __restrict__ wlrT,
                                              u16* __restrict__ w1T,
                                              u16* __restrict__ w2T,
                                              u16* __restrict__ canon,
                                              const int* __restrict__ flag) {
    int f32 = *flag;
    int i = blockIdx.x * 256 + threadIdx.x;
    if (i < 16384) {
        int r = i >> 7, c = i & 127;
        u16 v = f32 ? cleanf(((const float*)Wl)[i]) : cleanu(((const u16*)Wl)[i]);
        wlrT[c * 128 + r] = v;
    } else if (i < 32768) {
        int idx = i - 16384;
        int r = idx >> 7, c = idx & 127;
        u16 v = f32 ? cleanf(((const float*)Wr)[idx]) : cleanu(((const u16*)Wr)[idx]);
        wlrT[16384 + c * 128 + r] = v;
    } else if (i < 294912) {
        int idx = i - 32768;
        int r = idx >> 11, c = idx & 2047;    // [128][2048]
        u16 v = f32 ? cleanf(((const float*)W1)[idx]) : cleanu(((const u16*)W1)[idx]);
        w1T[c * 128 + r] = v;
    } else if (i < 557056) {
        int idx = i - 294912;
        int r = idx >> 7, c = idx & 127;      // [2048][128]
        u16 v = f32 ? cleanf(((const float*)W2)[idx]) : cleanu(((const u16*)W2)[idx]);
        w2T[c * 2048 + r] = v;
    } else if (i < 560256) {
        int p = i - 557056;
        const void* src; int off;
        if      (p < 128)  { src = bl;   off = 0; }
        else if (p < 256)  { src = br;   off = 128; }
        else if (p < 384)  { src = att;  off = 256; }
        else if (p < 512)  { src = bgat; off = 384; }
        else if (p < 2560) { src = b1;   off = 512; }
        else if (p < 2688) { src = b2;   off = 2560; }
        else if (p < 2816) { src = g1;   off = 2688; }
        else if (p < 2944) { src = be1;  off = 2816; }
        else if (p < 3072) { src = g2;   off = 2944; }
        else               { src = be2;  off = 3072; }
        int j = p - off;
        canon[p] = f32 ? cleanf(((const float*)src)[j]) : cleanu(((const u16*)src)[j]);
    }
}

// -------- CSR of the shared 7000-edge graph (dst-indexed); int32/int64 auto --------
__global__ __launch_bounds__(1024) void k_csr(const int* __restrict__ ew,
                                              int* __restrict__ row_off,
                                              int* __restrict__ col) {
    __shared__ int cnt[NNODE];
    __shared__ int offs[NNODE + 1];
    __shared__ int cur[NNODE];
    __shared__ int flag;
    int tid = threadIdx.x;
    if (tid == 0) flag = 0;
    for (int i = tid; i < NNODE; i += 1024) cnt[i] = 0;
    __syncthreads();
    int f = 0;
    for (int j = tid; j < EE; j += 1024) f |= ew[2 * j + 1];
    if (f) atomicOr(&flag, 1);
    __syncthreads();
    bool is32 = (flag != 0);
    for (int e = tid; e < EE; e += 1024) {
        int dst = is32 ? ew[EE + e] : ew[2 * EE + 2 * e];
        if ((unsigned)dst < NNODE) atomicAdd(&cnt[dst], 1);
    }
    __syncthreads();
    if (tid == 0) {
        int run = 0;
        for (int i = 0; i < NNODE; ++i) { offs[i] = run; run += cnt[i]; }
        offs[NNODE] = run;
    }
    __syncthreads();
    for (int i = tid; i < NNODE; i += 1024) cur[i] = offs[i];
    __syncthreads();
    for (int e = tid; e < EE; e += 1024) {
        int src = is32 ? ew[e] : ew[2 * e];
        int dst = is32 ? ew[EE + e] : ew[2 * EE + 2 * e];
        if ((unsigned)dst < NNODE && (unsigned)src < NNODE) {
            int p = atomicAdd(&cur[dst], 1);
            if (p < EE) col[p] = src;
        }
    }
    __syncthreads();
    for (int i = tid; i <= NNODE; i += 1024) row_off[i] = offs[i];
}

// -------- x_l / x_r: [TN,128] @ [128,256] via MFMA --------
__global__ __launch_bounds__(256) void k_linlr(const void* __restrict__ xraw,
                                               const u16* __restrict__ wlrT,  // [256][128]
                                               const u16* __restrict__ canon,
                                               u16* __restrict__ xl, u16* __restrict__ xr,
                                               const int* __restrict__ flag) {
    __shared__ __align__(16) u16 a_tile[64 * 136];
    int f32 = *flag;
    int tid = threadIdx.x;
    int m0 = blockIdx.x * 64;
    for (int it = 0; it < 4; ++it) {
        int idx = it * 256 + tid;
        int row = idx >> 4, cc = idx & 15;
        int gm = m0 + row;
        u16 tmp[8];
#pragma unroll
        for (int j = 0; j < 8; ++j) tmp[j] = 0;
        if (gm < TN) {
            size_t base = (size_t)gm * DD + cc * 8;
            if (f32) {
                float4 v0 = *(const float4*)((const float*)xraw + base);
                float4 v1 = *(const float4*)((const float*)xraw + base + 4);
                tmp[0] = cleanf(v0.x); tmp[1] = cleanf(v0.y);
                tmp[2] = cleanf(v0.z); tmp[3] = cleanf(v0.w);
                tmp[4] = cleanf(v1.x); tmp[5] = cleanf(v1.y);
                tmp[6] = cleanf(v1.z); tmp[7] = cleanf(v1.w);
            } else {
                uint4 v = *(const uint4*)((const u16*)xraw + base);
                unsigned wv[4] = {v.x, v.y, v.z, v.w};
#pragma unroll
                for (int j = 0; j < 8; ++j)
                    tmp[j] = cleanu((u16)((wv[j >> 1] >> ((j & 1) * 16)) & 0xFFFFu));
            }
        }
        uint4 o;
        o.x = (unsigned)tmp[0] | ((unsigned)tmp[1] << 16);
        o.y = (unsigned)tmp[2] | ((unsigned)tmp[3] << 16);
        o.z = (unsigned)tmp[4] | ((unsigned)tmp[5] << 16);
        o.w = (unsigned)tmp[6] | ((unsigned)tmp[7] << 16);
        *(uint4*)(a_tile + row * 136 + cc * 8) = o;
    }
    __syncthreads();
    int wave = tid >> 6, lane = tid & 63, n16 = lane & 15, q = lane >> 4;
    f32x4 acc[16];
#pragma unroll
    for (int t = 0; t < 16; ++t) acc[t] = (f32x4){0, 0, 0, 0};
    const u16* arow = a_tile + (16 * wave + n16) * 136;
#pragma unroll
    for (int ks = 0; ks < 4; ++ks) {
        bf16x8 a = *(const bf16x8*)(arow + ks * 32 + q * 8);
#pragma unroll
        for (int t = 0; t < 16; ++t) {
            bf16x8 b = *(const bf16x8*)(wlrT + ((size_t)(t * 16 + n16)) * DD + ks * 32 + q * 8);
            acc[t] = __builtin_amdgcn_mfma_f32_16x16x32_bf16(a, b, acc[t], 0, 0, 0);
        }
    }
#pragma unroll
    for (int t = 0; t < 16; ++t) {
        int cc = (t & 7) * 16 + n16;
        float bias = bf2f(canon[(t < 8 ? 0 : 128) + cc]);
        u16* dst = (t < 8 ? xl : xr);
#pragma unroll
        for (int reg = 0; reg < 4; ++reg) {
            int mrow = m0 + 16 * wave + 4 * q + reg;
            if (mrow < TN) dst[(size_t)mrow * DD + cc] = f2bf(acc[t][reg] + bias);
        }
    }
}

// -------- 16-lane segment sum --------
__device__ __forceinline__ float segsum16(float p) {
    p += __shfl_xor(p, 1, 16);
    p += __shfl_xor(p, 2, 16);
    p += __shfl_xor(p, 4, 16);
    p += __shfl_xor(p, 8, 16);
    return p;
}

// -------- GATv2: 1 wave/node, 2 packed channels/lane, no-max softmax --------
__global__ __launch_bounds__(256) void k_gat(const void* __restrict__ xraw,
                                             const u16* __restrict__ xl,
                                             const u16* xr,
                                             const u16* __restrict__ canon,
                                             const int* __restrict__ row_off,
                                             const int* __restrict__ col,
                                             u16* h1,
                                             const int* __restrict__ flag) {
    int f32 = *flag;
    int tid = threadIdx.x;
    int wave = tid >> 6, lane = tid & 63;
    int g = blockIdx.x * 4 + wave;             // TN % 4 == 0
    int bt = g / NNODE;
    int i = g - bt * NNODE;
    size_t gbase = (size_t)g * DD;
    const u16* xlrow0 = xl + (size_t)bt * NNODE * DD;
    int c2 = lane * 2;
    unsigned uxr = *(const unsigned*)(xr + gbase + c2);
    float xr0 = __uint_as_float(uxr << 16);
    float xr1 = __uint_as_float(uxr & 0xFFFF0000u);
    unsigned uat = *(const unsigned*)(canon + 256 + c2);
    float at0 = __uint_as_float(uat << 16);
    float at1 = __uint_as_float(uat & 0xFFFF0000u);
    unsigned uxs = *(const unsigned*)(xl + gbase + c2);
    float xs0 = __uint_as_float(uxs << 16);
    float xs1 = __uint_as_float(uxs & 0xFFFF0000u);
    float t0 = xs0 + xr0, t1 = xs1 + xr1;
    t0 = fmaxf(t0, 0.2f * t0); t1 = fmaxf(t1, 0.2f * t1);
    float p = t0 * at0 + t1 * at1;
    p += __shfl_xor(p, 1, 8);
    p += __shfl_xor(p, 2, 8);
    p += __shfl_xor(p, 4, 8);
    p = fminf(fmaxf(p, -30.f), 30.f);
    float w = __expf(p);
    float denom = w;
    float a0 = w * xs0, a1 = w * xs1;
    int r0 = row_off[i], r1 = row_off[i + 1];
    for (int e = r0; e < r1; ++e) {
        int j = __builtin_amdgcn_readfirstlane(col[e]);
        if ((unsigned)j >= NNODE) continue;
        unsigned uj = *(const unsigned*)(xlrow0 + (size_t)j * DD + c2);
        float x0 = __uint_as_float(uj << 16);
        float x1 = __uint_as_float(uj & 0xFFFF0000u);
        float u0 = x0 + xr0, u1 = x1 + xr1;
        u0 = fmaxf(u0, 0.2f * u0); u1 = fmaxf(u1, 0.2f * u1);
        float q = u0 * at0 + u1 * at1;
        q += __shfl_xor(q, 1, 8);
        q += __shfl_xor(q, 2, 8);
        q += __shfl_xor(q, 4, 8);
        q = fminf(fmaxf(q, -30.f), 30.f);
        float ww = __expf(q);
        denom += ww;
        a0 += ww * x0;
        a1 += ww * x1;
    }
    float inv = 1.f / denom;
    unsigned ubg = *(const unsigned*)(canon + 384 + c2);
    float res0, res1;
    if (f32) {
        float2 rr = *(const float2*)((const float*)xraw + gbase + c2);
        unsigned b0 = __float_as_uint(rr.x), b1 = __float_as_uint(rr.y);
        res0 = (((b0 >> 23) & 0xFF) == 0xFF) ? 0.f : rr.x;
        res1 = (((b1 >> 23) & 0xFF) == 0xFF) ? 0.f : rr.y;
    } else {
        unsigned ux = *(const unsigned*)((const u16*)xraw + gbase + c2);
        res0 = bf2f(cleanu((u16)(ux & 0xFFFFu)));
        res1 = bf2f(cleanu((u16)(ux >> 16)));
    }
    float pre0 = a0 * inv + __uint_as_float(ubg << 16) + res0;
    float pre1 = a1 * inv + __uint_as_float(ubg & 0xFFFF0000u) + res1;
    float sum = pre0 + pre1, sq = pre0 * pre0 + pre1 * pre1;
    for (int off = 32; off; off >>= 1) {
        sum += __shfl_xor(sum, off);
        sq  += __shfl_xor(sq, off);
    }
    float mu = sum * (1.0f / 128.0f);
    float var = fmaxf(sq * (1.0f / 128.0f) - mu * mu, 0.f);
    float rs = rsqrtf(var + 1e-5f);
    unsigned ug = *(const unsigned*)(canon + 2688 + c2);
    unsigned ub = *(const unsigned*)(canon + 2816 + c2);
    float h0 = (pre0 - mu) * rs * __uint_as_float(ug << 16) + __uint_as_float(ub << 16);
    float h1v = (pre1 - mu) * rs * __uint_as_float(ug & 0xFFFF0000u) + __uint_as_float(ub & 0xFFFF0000u);
    unsigned out = (unsigned)f2bf(h0) | ((unsigned)f2bf(h1v) << 16);
    *(unsigned*)(h1 + gbase + c2) = out;
}

// -------- fused FFN + residual + LN2: M=128/block, wave=32 rows --------
// Async DMA weight staging (swizzled); every w1b/w2b b-fragment feeds 2
// MFMAs (sub-tiles) -> LDS read traffic per MFMA halves vs M=64.
// LDS = 16384 + 16384 + 18432 = 51200 B -> 3 blocks/CU.
__global__ __launch_bounds__(256, 3) void k_ffn(const u16* __restrict__ h1,
                                                const u16* __restrict__ w1T,  // [2048][128]
                                                const u16* __restrict__ w2T,  // [128][2048]
                                                const u16* __restrict__ canon,
                                                void* __restrict__ outraw,
                                                const int* __restrict__ flag) {
    __shared__ __align__(16) u16 w1b[64 * 128];   // chunk of W1, swizzled
    __shared__ __align__(16) u16 w2b[128 * 64];   // chunk of W2, swizzled
    __shared__ __align__(16) u16 s_t[128 * 72];   // s = relu(h@W1+b1), padded
    int f32 = *flag;
    int tid = threadIdx.x;
    int wave = tid >> 6, lane = tid & 63, n16 = lane & 15, q = lane >> 4;
    int m0 = blockIdx.x * 128;
    int swz = n16 & 7;
    // A-fragments of h for this wave's 32 rows (2 sub-tiles), regs all kernel
    bf16x8 af[2][4];
#pragma unroll
    for (int sub = 0; sub < 2; ++sub) {
        int gm = m0 + 32 * wave + 16 * sub + n16;
#pragma unroll
        for (int ks = 0; ks < 4; ++ks) {
            if (gm < TN) {
                uint4 v = *(const uint4*)(h1 + (size_t)gm * DD + ks * 32 + q * 8);
                af[sub][ks] = *(const bf16x8*)&v;
            } else {
                uint4 z = make_uint4(0, 0, 0, 0);
                af[sub][ks] = *(const bf16x8*)&z;
            }
        }
    }
    f32x4 acc2[2][8];
#pragma unroll
    for (int sub = 0; sub < 2; ++sub)
#pragma unroll
        for (int t = 0; t < 8; ++t) acc2[sub][t] = (f32x4){0, 0, 0, 0};
    // DMA staging geometry (same as M=64 version; whole chunk per block)
    int w1r[4], w1b_log[4];
#pragma unroll
    for (int i = 0; i < 4; ++i) {
        w1r[i] = 16 * wave + 4 * i + (lane >> 4);
        w1b_log[i] = (lane & 15) ^ (w1r[i] & 7);
    }
    int w2r[4], w2b_log[4];
#pragma unroll
    for (int i = 0; i < 4; ++i) {
        w2r[i] = 32 * wave + 8 * i + (lane >> 3);
        w2b_log[i] = (lane & 7) ^ (w2r[i] & 7);
    }
    u16* srow_w0 = s_t + (32 * wave + 4 * q) * 72;        // sub0 write rows
    u16* srow_w1 = s_t + (32 * wave + 16 + 4 * q) * 72;   // sub1 write rows
    const u16* srow_r0 = s_t + (32 * wave + n16) * 72;
    const u16* srow_r1 = s_t + (32 * wave + 16 + n16) * 72;
    for (int ch = 0; ch < 32; ++ch) {
        int f0 = ch * 64;
        __syncthreads();   // prior chunk's consumers done
#pragma unroll
        for (int i = 0; i < 4; ++i) {
            glb_u16* g1 = (glb_u16*)(w1T + (size_t)(f0 + w1r[i]) * DD + w1b_log[i] * 8);
            lds_u16* l1 = (lds_u16*)(w1b + (16 * wave + 4 * i) * 128);
            __builtin_amdgcn_global_load_lds((const __attribute__((address_space(1))) unsigned*)g1,
                                             (__attribute__((address_space(3))) unsigned*)l1,
                                             16, 0, 0);
        }
#pragma unroll
        for (int i = 0; i < 4; ++i) {
            glb_u16* g2 = (glb_u16*)(w2T + (size_t)w2r[i] * FFDIM + f0 + w2b_log[i] * 8);
            lds_u16* l2 = (lds_u16*)(w2b + (32 * wave + 8 * i) * 64);
            __builtin_amdgcn_global_load_lds((const __attribute__((address_space(1))) unsigned*)g2,
                                             (__attribute__((address_space(3))) unsigned*)l2,
                                             16, 0, 0);
        }
        __syncthreads();   // drain: staged chunk visible
        // GEMM1: s = relu(h @ W1chunk + b1); each b-frag feeds both sub-tiles
#pragma unroll
        for (int t = 0; t < 4; ++t) {
            f32x4 a10 = (f32x4){0, 0, 0, 0};
            f32x4 a11 = (f32x4){0, 0, 0, 0};
#pragma unroll
            for (int ks = 0; ks < 4; ++ks) {
                bf16x8 b = *(const bf16x8*)(w1b + (t * 16 + n16) * 128 + (((ks * 4 + q) ^ swz) * 8));
                a10 = __builtin_amdgcn_mfma_f32_16x16x32_bf16(af[0][ks], b, a10, 0, 0, 0);
                a11 = __builtin_amdgcn_mfma_f32_16x16x32_bf16(af[1][ks], b, a11, 0, 0, 0);
            }
            float bb = bf2f(canon[512 + f0 + t * 16 + n16]);
#pragma unroll
            for (int reg = 0; reg < 4; ++reg) {
                float v0 = a10[reg] + bb;
                float v1 = a11[reg] + bb;
                v0 = v0 > 0.f ? v0 : 0.f;
                v1 = v1 > 0.f ? v1 : 0.f;
                srow_w0[reg * 72 + t * 16 + n16] = f2bf(v0);
                srow_w1[reg * 72 + t * 16 + n16] = f2bf(v1);
            }
        }
        asm volatile("" ::: "memory");
        // GEMM2: acc2 += s @ W2chunk (s rows wave-private; per-wave DS order ok)
#pragma unroll
        for (int ks2 = 0; ks2 < 2; ++ks2) {
            bf16x8 a20 = *(const bf16x8*)(srow_r0 + ks2 * 32 + q * 8);
            bf16x8 a21 = *(const bf16x8*)(srow_r1 + ks2 * 32 + q * 8);
#pragma unroll
            for (int t = 0; t < 8; ++t) {
                bf16x8 b = *(const bf16x8*)(w2b + (t * 16 + n16) * 64 + (((ks2 * 4 + q) ^ swz) * 8));
                acc2[0][t] = __builtin_amdgcn_mfma_f32_16x16x32_bf16(a20, b, acc2[0][t], 0, 0, 0);
                acc2[1][t] = __builtin_amdgcn_mfma_f32_16x16x32_bf16(a21, b, acc2[1][t], 0, 0, 0);
            }
        }
        asm volatile("" ::: "memory");
    }
    // epilogue: +b2 +residual, LN2 via 16-lane shuffles (row lives in one quad)
    float b2v[8], g2v[8], e2v[8];
#pragma unroll
    for (int t = 0; t < 8; ++t) {
        int col = t * 16 + n16;
        b2v[t] = bf2f(canon[2560 + col]);
        g2v[t] = bf2f(canon[2944 + col]);
        e2v[t] = bf2f(canon[3072 + col]);
    }
#pragma unroll
    for (int sub = 0; sub < 2; ++sub) {
#pragma unroll
        for (int reg = 0; reg < 4; ++reg) {
            int row = 32 * wave + 16 * sub + 4 * q + reg;
            int gm = m0 + row;
            bool ok = gm < TN;
            size_t gb = (size_t)(ok ? gm : 0) * DD;
            float v[8]; float s1 = 0.f, s2 = 0.f;
#pragma unroll
            for (int t = 0; t < 8; ++t) {
                float hres = bf2f(h1[gb + t * 16 + n16]);
                v[t] = acc2[sub][t][reg] + b2v[t] + hres;
                s1 += v[t]; s2 += v[t] * v[t];
            }
            s1 = segsum16(s1);
            s2 = segsum16(s2);
            float mu = s1 * (1.f / 128.f);
            float var = fmaxf(s2 * (1.f / 128.f) - mu * mu, 0.f);
            float rs = rsqrtf(var + 1e-5f);
            if (ok) {
#pragma unroll
                for (int t = 0; t < 8; ++t) {
                    float r = (v[t] - mu) * rs * g2v[t] + e2v[t];
                    if (f32) ((float*)outraw)[gb + t * 16 + n16] = r;
                    else     ((u16*)outraw)[gb + t * 16 + n16] = f2bf(r);
                }
            }
        }
    }
}

extern "C" void kernel_launch(void* const* d_in, const int* in_sizes, int n_in,
                              void* d_out, int out_size, void* d_ws, size_t ws_size,
                              hipStream_t stream) {
    const void* x    = d_in[0];
    const int* eidx  = (const int*)d_in[1];
    const void* Wl   = d_in[2];
    const void* bl   = d_in[3];
    const void* Wr   = d_in[4];
    const void* br   = d_in[5];
    const void* att  = d_in[6];
    const void* bgat = d_in[7];
    const void* W1   = d_in[8];
    const void* b1   = d_in[9];
    const void* W2   = d_in[10];
    const void* b2   = d_in[11];
    const void* g1   = d_in[12];
    const void* be1  = d_in[13];
    const void* g2   = d_in[14];
    const void* be2  = d_in[15];

    // ws layout (bytes): flag@0, rowoff@4096, colw@8192, canon@36864,
    // wlrT@65536, w1T@131072, w2T@655360, xl@1179648, xr/h1@22880256
    char* ws = (char*)d_ws;
    int* flag   = (int*)(ws);
    int* rowoff = (int*)(ws + 4096);
    int* colw   = (int*)(ws + 8192);
    u16* canon  = (u16*)(ws + 36864);
    u16* wlrT   = (u16*)(ws + 65536);
    u16* w1T    = (u16*)(ws + 131072);
    u16* w2T    = (u16*)(ws + 655360);
    u16* xl     = (u16*)(ws + 1179648);
    u16* xr     = (u16*)(ws + 22880256);
    u16* h1     = xr;   // k_gat reads xr[addr] before writing h1[addr]

    k_csr<<<1, 1024, 0, stream>>>(eidx, rowoff, colw);
    k_detect<<<1, 256, 0, stream>>>((const unsigned*)x, flag);
    k_prep<<<2189, 256, 0, stream>>>(Wl, Wr, W1, W2, bl, br, att, bgat, b1, b2,
                                     g1, be1, g2, be2, wlrT, w1T, w2T, canon, flag);
    k_linlr<<<(TN + 63) / 64, 256, 0, stream>>>(x, wlrT, canon, xl, xr, flag);
    k_gat<<<TN / 4, 256, 0, stream>>>(x, xl, xr, canon, rowoff, colw, h1, flag);
    k_ffn<<<(TN + 127) / 128, 256, 0, stream>>>(h1, w1T, w2T, canon, d_out, flag);
}